// Round 6
// baseline (54.020 us; speedup 1.0000x reference)
//
#include <hip/hip_runtime.h>
#include <hip/hip_bf16.h>

#define T_LEN   2000
#define NKER    256
#define LPAD    128          // padded l-dim (Lmax <= 127, slot 127 = bias tap)
#define NE      2128         // shifted entries built (>= T_LEN + Lmax - 1)
#define THREADS 512

typedef int   v4i __attribute__((ext_vector_type(4)));
typedef float v4f __attribute__((ext_vector_type(4)));

// ---- raw-asm MFMA: pins A/B/C in arch VGPRs (builtin let regalloc churn
// accs through AGPRs / remat A -> 2x slower, measured R5) ----
__device__ inline v4f mfma_z(v4i a, v4i b, v4f c) {
    v4f d;
    asm("v_mfma_f32_16x16x32_bf16 %0, %1, %2, %3" : "=v"(d) : "v"(a), "v"(b), "v"(c));
    return d;
}
__device__ inline void mfma_acc(v4f& acc, v4i a, v4i b) {
    asm("v_mfma_f32_16x16x32_bf16 %0, %1, %2, %0" : "+v"(acc) : "v"(a), "v"(b));
}
// chain-final MFMA: s_nop covers MFMA->VALU RAW hazard (opaque to compiler)
__device__ inline void mfma_acc_last(v4f& acc, v4i a, v4i b) {
    asm("v_mfma_f32_16x16x32_bf16 %0, %1, %2, %0\n\ts_nop 7"
        : "+v"(acc) : "v"(a), "v"(b));
}

__device__ inline unsigned f2bf(float f) {
    return (unsigned)__builtin_bit_cast(unsigned short, __float2bfloat16(f));
}

// ---------------------------------------------------------------------------
// Prep: dense bf16 weight bank [256][128], zero-padded, bias in slot l=127.
// 256 blocks x 64 threads; thread converts l=2t,2t+1 -> one dword (coalesced).
// ---------------------------------------------------------------------------
__global__ void rocket_prep(const float* __restrict__ W,
                            const float* __restrict__ bias, int Lmax,
                            unsigned* __restrict__ Wbf32) {
    const int k = blockIdx.x;
    const int t = threadIdx.x;           // 0..63
    const int l0 = 2 * t, l1 = 2 * t + 1;
    float v0 = (l0 < Lmax) ? W[k * Lmax + l0] : 0.0f;
    float v1 = (l1 < Lmax) ? W[k * Lmax + l1] : 0.0f;
    if (l1 == LPAD - 1) v1 = bias[k];    // bias tap (slot 127 always free)
    Wbf32[k * (LPAD / 2) + t] = f2bf(v0) | (f2bf(v1) << 16);
}

// ---------------------------------------------------------------------------
// Main: 256 blocks (one bc each) x 512 threads (8 waves).
// Wave = (khalf h, t-quarter tq): 128 kernels (8 ktiles), ~31 t-tiles of 16.
// LDS: 8-wide shifted bf16 entries, entry p (16B) = bf16{sx[p..p+7]} at
// uint4-index p + p/8. Per t-tile: 4 ds_read_b128 B-frags (double-buffered
// in registers: tile i+1's reads issue before tile i's MFMA chains ->
// ~120cy LDS latency hides under ~400cy compute), 32 MFMA, cnt/max epilogue.
// C layout (m89): row(kernel) = (lane>>4)*4 + reg, col(t) = lane&15.
// ---------------------------------------------------------------------------
__global__ __launch_bounds__(THREADS, 2) void rocket_main(
    const float* __restrict__ x, const unsigned short* __restrict__ Wbf,
    float* __restrict__ out, int Lmax) {

    __shared__ __align__(16) uint4 sx8[2400];     // idx max 2392
    __shared__ unsigned pc[NKER][4];
    __shared__ float    pm[NKER][4];

    const int bc  = blockIdx.x;
    const int tid = threadIdx.x;
    const int c0  = (Lmax - 1) >> 1;

    // ---- stage shifted entries: 5 consecutive entries per thread ----
    {
        const int base = tid * 5;
        if (base < NE) {
            float xv[12];
            #pragma unroll
            for (int i = 0; i < 12; ++i) {
                int s = base + i - c0;
                xv[i] = (s >= 0 && s < T_LEN) ? x[bc * T_LEN + s] : 0.0f;
            }
            unsigned hb[12];
            #pragma unroll
            for (int i = 0; i < 12; ++i) hb[i] = f2bf(xv[i]);
            #pragma unroll
            for (int i = 0; i < 5; ++i) {
                int p = base + i;
                if (p < NE) {
                    uint4 v;
                    v.x = hb[i]     | (hb[i + 1] << 16);
                    v.y = hb[i + 2] | (hb[i + 3] << 16);
                    v.z = hb[i + 4] | (hb[i + 5] << 16);
                    v.w = hb[i + 6] | (hb[i + 7] << 16);
                    sx8[p + (p >> 3)] = v;
                }
            }
        }
    }

    const int lane = tid & 63;
    const int wid  = tid >> 6;
    const int h    = wid & 1;        // kernel half
    const int tq   = wid >> 1;       // t quarter
    const int g    = lane >> 4;
    const int c    = lane & 15;

    // ---- A fragments: 8 ktiles x 4 k-steps, held in registers ----
    v4i afrag[8][4];
    #pragma unroll
    for (int kt = 0; kt < 8; ++kt) {
        #pragma unroll
        for (int s = 0; s < 4; ++s) {
            const unsigned short* src =
                Wbf + (h * 128 + kt * 16 + c) * LPAD + s * 32 + g * 8;
            afrag[kt][s] = *reinterpret_cast<const v4i*>(src);
        }
    }

    __syncthreads();

    unsigned cnt[8][4] = {};
    float    mx[8][4];
    #pragma unroll
    for (int kt = 0; kt < 8; ++kt)
        #pragma unroll
        for (int r = 0; r < 4; ++r) mx[kt][r] = -__builtin_inff();

    v4f zero4 = {0.f, 0.f, 0.f, 0.f};
    asm("" : "+v"(zero4));   // pin: persistent zero C-quad (no per-chain init)

    const int pb = g * 8 + c;                        // 0..39
    const unsigned voff = (unsigned)(pb + (pb >> 3)) << 4;
    const char* sxb = (const char*)sx8;

    const int tstart = (tq == 0) ? 0 : (1 + tq * 31); // 0,32,63,94
    const int tend   = tstart + ((tq == 0) ? 32 : 31);

    // prologue: load first tile's B-frags
    v4i bcur[4];
    #pragma unroll
    for (int s = 0; s < 4; ++s) {
        const int a = (tstart << 4) + (s << 5);
        const unsigned abyte = (unsigned)(a + (a >> 3)) << 4;
        bcur[s] = *reinterpret_cast<const v4i*>(sxb + abyte + voff);
    }

    #pragma unroll 1
    for (int tile = tstart; tile < tend; ++tile) {
        // ---- prefetch next tile's B-frags (hide ds_read latency) ----
        const int ntile = (tile + 1 < tend) ? tile + 1 : tstart;
        v4i bnxt[4];
        #pragma unroll
        for (int s = 0; s < 4; ++s) {
            const int a = (ntile << 4) + (s << 5);
            const unsigned abyte = (unsigned)(a + (a >> 3)) << 4;
            bnxt[s] = *reinterpret_cast<const v4i*>(sxb + abyte + voff);
        }

        // bias tap: element (g=3, j=7) of s=3 frag must be 1.0 (pairs with
        // Wbf[k][127] = bias).
        if (g == 3)
            bcur[3][3] = (bcur[3][3] & 0xffff) | 0x3f800000;

        #pragma unroll
        for (int kt = 0; kt < 8; ++kt) {
            v4f acc = mfma_z(afrag[kt][0], bcur[0], zero4);
            mfma_acc(acc, afrag[kt][1], bcur[1]);
            mfma_acc(acc, afrag[kt][2], bcur[2]);
            mfma_acc_last(acc, afrag[kt][3], bcur[3]);
            #pragma unroll
            for (int r = 0; r < 4; ++r) {
                cnt[kt][r] += (acc[r] > 0.0f) ? 1u : 0u;
                mx[kt][r]  = fmaxf(mx[kt][r], acc[r]);
            }
        }

        #pragma unroll
        for (int s = 0; s < 4; ++s) bcur[s] = bnxt[s];
    }

    // ---- col reduce over 16 lanes via DPP row_ror (no LDS pipe) ----
    #pragma unroll
    for (int kt = 0; kt < 8; ++kt) {
        #pragma unroll
        for (int r = 0; r < 4; ++r) {
            unsigned cv = cnt[kt][r];
            cv += (unsigned)__builtin_amdgcn_update_dpp(0, (int)cv, 0x128, 0xF, 0xF, true);
            cv += (unsigned)__builtin_amdgcn_update_dpp(0, (int)cv, 0x124, 0xF, 0xF, true);
            cv += (unsigned)__builtin_amdgcn_update_dpp(0, (int)cv, 0x122, 0xF, 0xF, true);
            cv += (unsigned)__builtin_amdgcn_update_dpp(0, (int)cv, 0x121, 0xF, 0xF, true);
            float mv = mx[kt][r];
            mv = fmaxf(mv, __builtin_bit_cast(float,
                 __builtin_amdgcn_update_dpp(0, __builtin_bit_cast(int, mv), 0x128, 0xF, 0xF, true)));
            mv = fmaxf(mv, __builtin_bit_cast(float,
                 __builtin_amdgcn_update_dpp(0, __builtin_bit_cast(int, mv), 0x124, 0xF, 0xF, true)));
            mv = fmaxf(mv, __builtin_bit_cast(float,
                 __builtin_amdgcn_update_dpp(0, __builtin_bit_cast(int, mv), 0x122, 0xF, 0xF, true)));
            mv = fmaxf(mv, __builtin_bit_cast(float,
                 __builtin_amdgcn_update_dpp(0, __builtin_bit_cast(int, mv), 0x121, 0xF, 0xF, true)));
            if (c == 0) {
                const int kk = h * 128 + kt * 16 + g * 4 + r;
                pc[kk][tq] = cv;
                pm[kk][tq] = mv;
            }
        }
    }
    __syncthreads();

    if (tid < NKER) {
        unsigned ct = pc[tid][0] + pc[tid][1] + pc[tid][2] + pc[tid][3];
        float mv = fmaxf(fmaxf(pm[tid][0], pm[tid][1]),
                         fmaxf(pm[tid][2], pm[tid][3]));
        out[bc * (2 * NKER) + 2 * tid]     = (float)ct * (1.0f / T_LEN);
        out[bc * (2 * NKER) + 2 * tid + 1] = mv;
    }
}

extern "C" void kernel_launch(void* const* d_in, const int* in_sizes, int n_in,
                              void* d_out, int out_size, void* d_ws, size_t ws_size,
                              hipStream_t stream) {
    const float* x    = (const float*)d_in[0];
    const float* W    = (const float*)d_in[1];
    const float* bias = (const float*)d_in[2];
    float*       out  = (float*)d_out;

    const int Lmax = in_sizes[1] / NKER;

    unsigned* Wbf32 = (unsigned*)d_ws;             // 256*128*2 = 64 KB

    rocket_prep<<<dim3(NKER), dim3(64), 0, stream>>>(W, bias, Lmax, Wbf32);
    rocket_main<<<dim3(256), dim3(THREADS), 0, stream>>>(
        x, (const unsigned short*)Wbf32, out, Lmax);
}

// Round 8
// 49.038 us; speedup vs baseline: 1.1016x; 1.1016x over previous
//
#include <hip/hip_runtime.h>
#include <hip/hip_bf16.h>

#define T_LEN   2000
#define NKER    256
#define LPAD    128          // padded l-dim (Lmax <= 127, slot 127 = bias tap)
#define NE      2128         // shifted entries built (>= T_LEN + Lmax - 1)
#define THREADS 512

typedef int   v4i __attribute__((ext_vector_type(4)));
typedef float v4f __attribute__((ext_vector_type(4)));

// raw-asm MFMA. CORRECTNESS: "=&v" early-clobber on mfma_z -- without it the
// allocator may alias D with a dying A/B input (legal for plain VALU, ILLEGAL
// for multi-pass XDL: D must not overlap A/B). R7's absmax=4.3 failure traced
// to d = bcur[0]'s regs at bcur[0]'s last use. volatile: forbid dup/motion.
__device__ inline v4f mfma_z(v4i a, v4i b, v4f c) {
    v4f d;
    asm volatile("v_mfma_f32_16x16x32_bf16 %0, %1, %2, %3"
                 : "=&v"(d) : "v"(a), "v"(b), "v"(c));
    return d;
}
__device__ inline void mfma_acc(v4f& acc, v4i a, v4i b) {
    asm volatile("v_mfma_f32_16x16x32_bf16 %0, %1, %2, %0"
                 : "+v"(acc) : "v"(a), "v"(b));
}
// chain-final MFMA: s_nop covers MFMA->VALU RAW hazard (opaque to compiler)
__device__ inline void mfma_acc_last(v4f& acc, v4i a, v4i b) {
    asm volatile("v_mfma_f32_16x16x32_bf16 %0, %1, %2, %0\n\ts_nop 7"
                 : "+v"(acc) : "v"(a), "v"(b));
}

__device__ inline unsigned f2bf(float f) {
    return (unsigned)__builtin_bit_cast(unsigned short, __float2bfloat16(f));
}

// ---------------------------------------------------------------------------
// Prep: dense bf16 weight bank [256][128], zero-padded, bias in slot l=127.
// 256 blocks x 64 threads; thread converts l=2t,2t+1 -> one dword (coalesced).
// ---------------------------------------------------------------------------
__global__ void rocket_prep(const float* __restrict__ W,
                            const float* __restrict__ bias, int Lmax,
                            unsigned* __restrict__ Wbf32) {
    const int k = blockIdx.x;
    const int t = threadIdx.x;           // 0..63
    const int l0 = 2 * t, l1 = 2 * t + 1;
    float v0 = (l0 < Lmax) ? W[k * Lmax + l0] : 0.0f;
    float v1 = (l1 < Lmax) ? W[k * Lmax + l1] : 0.0f;
    if (l1 == LPAD - 1) v1 = bias[k];    // bias tap (slot 127 always free)
    Wbf32[k * (LPAD / 2) + t] = f2bf(v0) | (f2bf(v1) << 16);
}

// ---------------------------------------------------------------------------
// Main: grid (256 bc, 4 sub) x 512 threads (8 waves).
// Block covers kernels [sub*64, sub*64+64). Wave = (kp = wid>>2, tq = wid&3):
// 2 ktiles (32 kernels) x ~31 t-tiles. Small per-wave register tile
// (afrag 32 + cnt/mx 16 + bcur 16, fits 128-VGPR cap, no A remat) ->
// 4 waves/SIMD. LDS: 8-wide shifted bf16 entries, entry p (16B) =
// bf16{sx[p..p+7]} at uint4-index p + p/8. Per t-tile: 4 ds_read_b128
// B-frags, 8 MFMA (2 chains), cnt/max epilogue.
// C layout (m89): row(k) = g*4 + r, col(t) = c.
// ---------------------------------------------------------------------------
__global__ __launch_bounds__(THREADS, 4) void rocket_main(
    const float* __restrict__ x, const unsigned short* __restrict__ Wbf,
    float* __restrict__ out, int Lmax) {

    __shared__ __align__(16) uint4 sx8[2400];     // idx max 2392
    __shared__ unsigned pc[64][4];
    __shared__ float    pm[64][4];

    const int bc  = blockIdx.x;
    const int sub = blockIdx.y;          // kernel group of 64
    const int tid = threadIdx.x;
    const int c0  = (Lmax - 1) >> 1;

    // ---- stage shifted entries: 5 consecutive entries per thread ----
    {
        const int base = tid * 5;
        if (base < NE) {
            float xv[12];
            #pragma unroll
            for (int i = 0; i < 12; ++i) {
                int s = base + i - c0;
                xv[i] = (s >= 0 && s < T_LEN) ? x[bc * T_LEN + s] : 0.0f;
            }
            unsigned hb[12];
            #pragma unroll
            for (int i = 0; i < 12; ++i) hb[i] = f2bf(xv[i]);
            #pragma unroll
            for (int i = 0; i < 5; ++i) {
                int p = base + i;
                if (p < NE) {
                    uint4 v;
                    v.x = hb[i]     | (hb[i + 1] << 16);
                    v.y = hb[i + 2] | (hb[i + 3] << 16);
                    v.z = hb[i + 4] | (hb[i + 5] << 16);
                    v.w = hb[i + 6] | (hb[i + 7] << 16);
                    sx8[p + (p >> 3)] = v;
                }
            }
        }
    }

    const int lane = tid & 63;
    const int wid  = tid >> 6;
    const int kp   = wid >> 2;       // 0..1: local ktile-pair
    const int tq   = wid & 3;        // t quarter
    const int g    = lane >> 4;
    const int c    = lane & 15;

    // ---- A fragments: 2 ktiles x 4 k-steps in registers (32 VGPR) ----
    v4i afrag[2][4];
    #pragma unroll
    for (int kt = 0; kt < 2; ++kt) {
        #pragma unroll
        for (int s = 0; s < 4; ++s) {
            const unsigned short* src =
                Wbf + ((sub * 4 + kp * 2 + kt) * 16 + c) * LPAD + s * 32 + g * 8;
            afrag[kt][s] = *reinterpret_cast<const v4i*>(src);
        }
    }

    __syncthreads();

    unsigned cnt[2][4] = {};
    float    mx[2][4];
    #pragma unroll
    for (int kt = 0; kt < 2; ++kt)
        #pragma unroll
        for (int r = 0; r < 4; ++r) mx[kt][r] = -__builtin_inff();

    v4f zero4 = {0.f, 0.f, 0.f, 0.f};
    asm("" : "+v"(zero4));   // pin: persistent zero C-quad

    const int pb = g * 8 + c;                        // 0..39
    const unsigned voff = (unsigned)(pb + (pb >> 3)) << 4;
    const char* sxb = (const char*)sx8;

    const int tstart = (tq == 0) ? 0 : (1 + tq * 31); // 0,32,63,94
    const int tend   = tstart + ((tq == 0) ? 32 : 31);

    #pragma unroll 1
    for (int tile = tstart; tile < tend; ++tile) {
        const int t0 = tile << 4;
        v4i bcur[4];
        #pragma unroll
        for (int s = 0; s < 4; ++s) {
            const int a = t0 + (s << 5);                   // mult of 8
            const unsigned abyte = (unsigned)(a + (a >> 3)) << 4;
            bcur[s] = *reinterpret_cast<const v4i*>(sxb + abyte + voff);
        }
        // bias tap: element (g=3, j=7) of s=3 frag = 1.0 (pairs with
        // Wbf[k][127] = bias)
        if (g == 3)
            bcur[3][3] = (bcur[3][3] & 0xffff) | 0x3f800000;

        #pragma unroll
        for (int kt = 0; kt < 2; ++kt) {
            v4f acc = mfma_z(afrag[kt][0], bcur[0], zero4);
            mfma_acc(acc, afrag[kt][1], bcur[1]);
            mfma_acc(acc, afrag[kt][2], bcur[2]);
            mfma_acc_last(acc, afrag[kt][3], bcur[3]);
            #pragma unroll
            for (int r = 0; r < 4; ++r) {
                cnt[kt][r] += (acc[r] > 0.0f) ? 1u : 0u;
                mx[kt][r]  = fmaxf(mx[kt][r], acc[r]);
            }
        }
    }

    // ---- col reduce over 16 lanes via DPP row_ror (no LDS pipe) ----
    #pragma unroll
    for (int kt = 0; kt < 2; ++kt) {
        #pragma unroll
        for (int r = 0; r < 4; ++r) {
            unsigned cv = cnt[kt][r];
            cv += (unsigned)__builtin_amdgcn_update_dpp(0, (int)cv, 0x128, 0xF, 0xF, true);
            cv += (unsigned)__builtin_amdgcn_update_dpp(0, (int)cv, 0x124, 0xF, 0xF, true);
            cv += (unsigned)__builtin_amdgcn_update_dpp(0, (int)cv, 0x122, 0xF, 0xF, true);
            cv += (unsigned)__builtin_amdgcn_update_dpp(0, (int)cv, 0x121, 0xF, 0xF, true);
            float mv = mx[kt][r];
            mv = fmaxf(mv, __builtin_bit_cast(float,
                 __builtin_amdgcn_update_dpp(0, __builtin_bit_cast(int, mv), 0x128, 0xF, 0xF, true)));
            mv = fmaxf(mv, __builtin_bit_cast(float,
                 __builtin_amdgcn_update_dpp(0, __builtin_bit_cast(int, mv), 0x124, 0xF, 0xF, true)));
            mv = fmaxf(mv, __builtin_bit_cast(float,
                 __builtin_amdgcn_update_dpp(0, __builtin_bit_cast(int, mv), 0x122, 0xF, 0xF, true)));
            mv = fmaxf(mv, __builtin_bit_cast(float,
                 __builtin_amdgcn_update_dpp(0, __builtin_bit_cast(int, mv), 0x121, 0xF, 0xF, true)));
            if (c == 0) {
                const int klo = (kp * 2 + kt) * 16 + g * 4 + r;   // 0..63
                pc[klo][tq] = cv;
                pm[klo][tq] = mv;
            }
        }
    }
    __syncthreads();

    if (tid < 64) {
        unsigned ct = pc[tid][0] + pc[tid][1] + pc[tid][2] + pc[tid][3];
        float mv = fmaxf(fmaxf(pm[tid][0], pm[tid][1]),
                         fmaxf(pm[tid][2], pm[tid][3]));
        const int kk = sub * 64 + tid;
        out[bc * (2 * NKER) + 2 * kk]     = (float)ct * (1.0f / T_LEN);
        out[bc * (2 * NKER) + 2 * kk + 1] = mv;
    }
}

extern "C" void kernel_launch(void* const* d_in, const int* in_sizes, int n_in,
                              void* d_out, int out_size, void* d_ws, size_t ws_size,
                              hipStream_t stream) {
    const float* x    = (const float*)d_in[0];
    const float* W    = (const float*)d_in[1];
    const float* bias = (const float*)d_in[2];
    float*       out  = (float*)d_out;

    const int Lmax = in_sizes[1] / NKER;

    unsigned* Wbf32 = (unsigned*)d_ws;             // 256*128*2 = 64 KB

    rocket_prep<<<dim3(NKER), dim3(64), 0, stream>>>(W, bias, Lmax, Wbf32);
    rocket_main<<<dim3(256, 4), dim3(THREADS), 0, stream>>>(
        x, (const unsigned short*)Wbf32, out, Lmax);
}

// Round 9
// 37.319 us; speedup vs baseline: 1.4475x; 1.3140x over previous
//
#include <hip/hip_runtime.h>
#include <hip/hip_bf16.h>

#define T_LEN   2000
#define NKER    256
#define LPAD    128          // padded l-dim (Lmax <= 127)
#define NE      2128         // shifted entries staged (>= T_LEN + Lmax - 1)
#define THREADS 512

typedef int   v4i __attribute__((ext_vector_type(4)));
typedef float v4f __attribute__((ext_vector_type(4)));

// raw-asm MFMA. "=&v" early-clobber: D must not alias A/B (multi-pass XDL);
// R7's absmax=4.3 failure was the allocator aliasing D with a dying B input.
__device__ inline v4f mfma_z(v4i a, v4i b, v4f c) {
    v4f d;
    asm volatile("v_mfma_f32_16x16x32_bf16 %0, %1, %2, %3"
                 : "=&v"(d) : "v"(a), "v"(b), "v"(c));
    return d;
}
__device__ inline void mfma_acc(v4f& acc, v4i a, v4i b) {
    asm volatile("v_mfma_f32_16x16x32_bf16 %0, %1, %2, %0"
                 : "+v"(acc) : "v"(a), "v"(b));
}
// chain-final MFMA: s_nop covers MFMA->VALU RAW hazard (opaque to compiler)
__device__ inline void mfma_acc_last(v4f& acc, v4i a, v4i b) {
    asm volatile("v_mfma_f32_16x16x32_bf16 %0, %1, %2, %0\n\ts_nop 7"
                 : "+v"(acc) : "v"(a), "v"(b));
}

__device__ inline unsigned f2bf(float f) {
    return (unsigned)__builtin_bit_cast(unsigned short, __float2bfloat16(f));
}

// ---------------------------------------------------------------------------
// Prep: dense bf16 weight bank [256][128], zero-padded (no bias tap -- bias
// is applied in the main epilogue: cnt uses acc > -b, max adds b at the end).
// ---------------------------------------------------------------------------
__global__ void rocket_prep(const float* __restrict__ W, int Lmax,
                            unsigned* __restrict__ Wbf32) {
    const int k = blockIdx.x;
    const int t = threadIdx.x;           // 0..63
    const int l0 = 2 * t, l1 = 2 * t + 1;
    float v0 = (l0 < Lmax) ? W[k * Lmax + l0] : 0.0f;
    float v1 = (l1 < Lmax) ? W[k * Lmax + l1] : 0.0f;
    Wbf32[k * (LPAD / 2) + t] = f2bf(v0) | (f2bf(v1) << 16);
}

// ---------------------------------------------------------------------------
// Main: grid (256 bc, 4 sub) x 512 threads (8 waves = 2 kp x 4 tq).
// Wave: 2 ktiles (32 kernels) x 32/29 t-tiles (split 32/32/32/29).
// B-entry for (tile tau, slot s) is J = tau + 2s at LDS byte 288*J + voff --
// an arithmetic progression. 8-deep per-lane register window w[J%8] turns
// 4 ds_read_b128/tile into 1/tile (steady state), with all addresses folded
// to base + compile-time immediates. Epilogue: cnt += (acc > -bias), running
// max; DPP row_ror 16-lane column reduce; bias added to max at final write.
// ---------------------------------------------------------------------------
__global__ __launch_bounds__(THREADS, 4) void rocket_main(
    const float* __restrict__ x, const float* __restrict__ bias,
    const unsigned short* __restrict__ Wbf, float* __restrict__ out,
    int Lmax) {

    __shared__ __align__(16) uint4 sx8[2400];     // idx max 2392
    __shared__ unsigned pc[64][4];
    __shared__ float    pm[64][4];

    const int bc  = blockIdx.x;
    const int sub = blockIdx.y;          // kernel group of 64
    const int tid = threadIdx.x;
    const int c0  = (Lmax - 1) >> 1;

    // ---- stage shifted entries: 5 consecutive entries per thread ----
    {
        const int base = tid * 5;
        if (base < NE) {
            float xv[12];
            #pragma unroll
            for (int i = 0; i < 12; ++i) {
                int s = base + i - c0;
                xv[i] = (s >= 0 && s < T_LEN) ? x[bc * T_LEN + s] : 0.0f;
            }
            unsigned hb[12];
            #pragma unroll
            for (int i = 0; i < 12; ++i) hb[i] = f2bf(xv[i]);
            #pragma unroll
            for (int i = 0; i < 5; ++i) {
                int p = base + i;
                if (p < NE) {
                    uint4 v;
                    v.x = hb[i]     | (hb[i + 1] << 16);
                    v.y = hb[i + 2] | (hb[i + 3] << 16);
                    v.z = hb[i + 4] | (hb[i + 5] << 16);
                    v.w = hb[i + 6] | (hb[i + 7] << 16);
                    sx8[p + (p >> 3)] = v;
                }
            }
        }
    }

    const int lane = tid & 63;
    const int wid  = tid >> 6;
    const int kp   = wid >> 2;       // 0..1: local ktile-pair
    const int tq   = wid & 3;        // t quarter
    const int g    = lane >> 4;
    const int c    = lane & 15;

    // ---- A fragments: 2 ktiles x 4 k-steps in registers (32 VGPR) ----
    v4i afrag[2][4];
    #pragma unroll
    for (int kt = 0; kt < 2; ++kt) {
        #pragma unroll
        for (int s = 0; s < 4; ++s) {
            const unsigned short* src =
                Wbf + ((sub * 4 + kp * 2 + kt) * 16 + c) * LPAD + s * 32 + g * 8;
            afrag[kt][s] = *reinterpret_cast<const v4i*>(src);
        }
    }

    // ---- negated bias per owned row: nb[kt][r] for rows g*4+r ----
    float nb[2][4];
    #pragma unroll
    for (int kt = 0; kt < 2; ++kt) {
        float4 bv = *reinterpret_cast<const float4*>(
            bias + sub * 64 + (kp * 2 + kt) * 16 + g * 4);
        nb[kt][0] = -bv.x; nb[kt][1] = -bv.y;
        nb[kt][2] = -bv.z; nb[kt][3] = -bv.w;
    }

    __syncthreads();

    unsigned cnt[2][4] = {};
    float    mx[2][4];
    #pragma unroll
    for (int kt = 0; kt < 2; ++kt)
        #pragma unroll
        for (int r = 0; r < 4; ++r) mx[kt][r] = -__builtin_inff();

    v4f zero4 = {0.f, 0.f, 0.f, 0.f};
    asm("" : "+v"(zero4));   // pin: persistent zero C-quad

    const int pb = g * 8 + c;                        // 0..39
    const unsigned voff = (unsigned)(pb + (pb >> 3)) << 4;

    // per-tile compute: 2 chains of 4 MFMA + cnt/max epilogue
    auto do_tile = [&](v4i b0, v4i b1, v4i b2, v4i b3) {
        #pragma unroll
        for (int kt = 0; kt < 2; ++kt) {
            v4f acc = mfma_z(afrag[kt][0], b0, zero4);
            mfma_acc(acc, afrag[kt][1], b1);
            mfma_acc(acc, afrag[kt][2], b2);
            mfma_acc_last(acc, afrag[kt][3], b3);
            #pragma unroll
            for (int r = 0; r < 4; ++r) {
                cnt[kt][r] += (acc[r] > nb[kt][r]) ? 1u : 0u;
                mx[kt][r]  = fmaxf(mx[kt][r], acc[r]);
            }
        }
    };

    const int tstart = tq * 32;                      // 32/32/32/29 split
    const int nms    = (tq == 3) ? 3 : 4;            // 8-tile macro-steps

    // entry J lives at byte 288*J + voff (idx = 18J + pb + (pb>>3))
    const char* p = (const char*)sx8 + voff + 288u * (unsigned)tstart;

    // ---- window prologue: J = tstart..tstart+7 in slots 0..7 ----
    v4i w[8];
    #pragma unroll
    for (int j = 0; j < 8; ++j)
        w[j] = *reinterpret_cast<const v4i*>(p + 288 * j);

    #pragma unroll 1
    for (int ms = 0; ms < nms; ++ms) {
        #pragma unroll
        for (int m = 0; m < 4; ++m) {
            // tile 2m: slots (2m+2s)&7
            do_tile(w[(2*m + 0) & 7], w[(2*m + 2) & 7],
                    w[(2*m + 4) & 7], w[(2*m + 6) & 7]);
            // tile 2m+1: slots (2m+1+2s)&7
            do_tile(w[(2*m + 1) & 7], w[(2*m + 3) & 7],
                    w[(2*m + 5) & 7], w[(2*m + 7) & 7]);
            // slide: J+8, J+9 into freed slots
            w[(2*m + 0) & 7] = *reinterpret_cast<const v4i*>(p + 288 * (2*m + 8));
            w[(2*m + 1) & 7] = *reinterpret_cast<const v4i*>(p + 288 * (2*m + 9));
        }
        p += 2304;                                   // 8 tiles * 288
    }

    if (tq == 3) {
        // tail tiles 120..124 (rel 0..4 from p): plain 4-read path
        #pragma unroll
        for (int tt = 0; tt < 5; ++tt) {
            v4i b0 = *reinterpret_cast<const v4i*>(p + 288 * (tt + 0));
            v4i b1 = *reinterpret_cast<const v4i*>(p + 288 * (tt + 2));
            v4i b2 = *reinterpret_cast<const v4i*>(p + 288 * (tt + 4));
            v4i b3 = *reinterpret_cast<const v4i*>(p + 288 * (tt + 6));
            do_tile(b0, b1, b2, b3);
        }
    }

    // ---- col reduce over 16 lanes via DPP row_ror (no LDS pipe) ----
    #pragma unroll
    for (int kt = 0; kt < 2; ++kt) {
        #pragma unroll
        for (int r = 0; r < 4; ++r) {
            unsigned cv = cnt[kt][r];
            cv += (unsigned)__builtin_amdgcn_update_dpp(0, (int)cv, 0x128, 0xF, 0xF, true);
            cv += (unsigned)__builtin_amdgcn_update_dpp(0, (int)cv, 0x124, 0xF, 0xF, true);
            cv += (unsigned)__builtin_amdgcn_update_dpp(0, (int)cv, 0x122, 0xF, 0xF, true);
            cv += (unsigned)__builtin_amdgcn_update_dpp(0, (int)cv, 0x121, 0xF, 0xF, true);
            float mv = mx[kt][r];
            mv = fmaxf(mv, __builtin_bit_cast(float,
                 __builtin_amdgcn_update_dpp(0, __builtin_bit_cast(int, mv), 0x128, 0xF, 0xF, true)));
            mv = fmaxf(mv, __builtin_bit_cast(float,
                 __builtin_amdgcn_update_dpp(0, __builtin_bit_cast(int, mv), 0x124, 0xF, 0xF, true)));
            mv = fmaxf(mv, __builtin_bit_cast(float,
                 __builtin_amdgcn_update_dpp(0, __builtin_bit_cast(int, mv), 0x122, 0xF, 0xF, true)));
            mv = fmaxf(mv, __builtin_bit_cast(float,
                 __builtin_amdgcn_update_dpp(0, __builtin_bit_cast(int, mv), 0x121, 0xF, 0xF, true)));
            if (c == 0) {
                const int klo = (kp * 2 + kt) * 16 + g * 4 + r;   // 0..63
                pc[klo][tq] = cv;
                pm[klo][tq] = mv;
            }
        }
    }
    __syncthreads();

    if (tid < 64) {
        unsigned ct = pc[tid][0] + pc[tid][1] + pc[tid][2] + pc[tid][3];
        float mv = fmaxf(fmaxf(pm[tid][0], pm[tid][1]),
                         fmaxf(pm[tid][2], pm[tid][3]));
        const int kk = sub * 64 + tid;
        out[bc * (2 * NKER) + 2 * kk]     = (float)ct * (1.0f / T_LEN);
        out[bc * (2 * NKER) + 2 * kk + 1] = mv + bias[kk];   // bias folded here
    }
}

extern "C" void kernel_launch(void* const* d_in, const int* in_sizes, int n_in,
                              void* d_out, int out_size, void* d_ws, size_t ws_size,
                              hipStream_t stream) {
    const float* x    = (const float*)d_in[0];
    const float* W    = (const float*)d_in[1];
    const float* bias = (const float*)d_in[2];
    float*       out  = (float*)d_out;

    const int Lmax = in_sizes[1] / NKER;

    unsigned* Wbf32 = (unsigned*)d_ws;             // 256*128*2 = 64 KB

    rocket_prep<<<dim3(NKER), dim3(64), 0, stream>>>(W, Lmax, Wbf32);
    rocket_main<<<dim3(256, 4), dim3(THREADS), 0, stream>>>(
        x, bias, (const unsigned short*)Wbf32, out, Lmax);
}